// Round 2
// baseline (252.612 us; speedup 1.0000x reference)
//
#include <hip/hip_runtime.h>
#include <stdint.h>

// Cheb graph conv: out[b,o,m,t] = sum_{k,n,c} T_k[n,m] x[b,c,n,t] Theta[k,c,o]
// Folded:  W[(o,m)][(c,n)] = sum_k T_k[n,m] Theta[k,c,o]   (768x768, bf16)
//          out_b (768x512) = W @ x_b (768x512)   for each of 64 batches.
// bf16 MFMA GEMM (m97 structure: 128x128 tile, BK=32, global_load_lds w=16).

#define NV 24
#define CIN 32
#define COUT 32
#define TDIM 512
#define BATCH 64
#define MDIM 768   // COUT*NV (out rows per batch)
#define KD 768     // CIN*NV  (reduction dim)
#define BM 128
#define BN 128
#define BK 32

typedef __attribute__((ext_vector_type(8))) short short8v;  // 8 bf16 (4 VGPRs)
typedef __attribute__((ext_vector_type(4))) float float4v;  // 4 fp32 acc

__device__ inline unsigned short f2bf(float f) {
    // round-to-nearest-even f32 -> bf16 (inputs are finite gaussians; no NaN path)
    unsigned int u = __float_as_uint(f);
    unsigned int r = (u + 0x7fffu + ((u >> 16) & 1u)) >> 16;
    return (unsigned short)r;
}

// ---------------------------------------------------------------------------
// prep_w: 64 blocks x 256 thr. Each block redundantly computes L, T2 (tiny),
// then writes 12 rows of W (bf16).
// NOTE: NV*NV=576 > 256 threads -> every per-element phase MUST be a strided
// loop, not an `if (tid < 576)` guard (round-1 NaN root cause).
__global__ __launch_bounds__(256) void prep_w(const float* __restrict__ adj,
                                              const float* __restrict__ Theta,
                                              unsigned short* __restrict__ W) {
    __shared__ float adjS[NV * NV];
    __shared__ float disS[NV];
    __shared__ float LS[NV * NV];
    __shared__ float T2S[NV * NV];
    int tid = threadIdx.x;
    for (int e = tid; e < NV * NV; e += 256) adjS[e] = adj[e];
    __syncthreads();
    if (tid < NV) {
        float d = 0.f;
        for (int j = 0; j < NV; ++j) d += adjS[tid * NV + j];
        disS[tid] = (d > 0.f) ? rsqrtf(d) : 0.f;
    }
    __syncthreads();
    for (int e = tid; e < NV * NV; e += 256) {
        int i = e / NV, j = e % NV;
        // L[i][j] = dis[i] * adj[j][i] * dis[j]
        LS[e] = disS[i] * adjS[j * NV + i] * disS[j];
    }
    __syncthreads();
    for (int e = tid; e < NV * NV; e += 256) {
        int i = e / NV, j = e % NV;
        float s = 0.f;
        for (int p = 0; p < NV; ++p) s += LS[i * NV + p] * LS[p * NV + j];
        T2S[e] = 2.f * s - (i == j ? 1.f : 0.f);
    }
    __syncthreads();
    int r0 = blockIdx.x * (MDIM / 64);  // 12 rows per block
    for (int e = tid; e < (MDIM / 64) * KD; e += 256) {
        int lr = e / KD, col = e % KD;
        int row = r0 + lr;
        int o = row / NV, m = row % NV;
        int c = col / NV, n = col % NV;
        float th0 = Theta[0 * CIN * COUT + c * COUT + o];
        float th1 = Theta[1 * CIN * COUT + c * COUT + o];
        float th2 = Theta[2 * CIN * COUT + c * COUT + o];
        float v = (n == m ? th0 : 0.f) + LS[n * NV + m] * th1 + T2S[n * NV + m] * th2;
        W[(size_t)row * KD + col] = f2bf(v);
    }
}

// ---------------------------------------------------------------------------
// convert_xT: x[b][cn][t] fp32 -> xT[b][t][cn] bf16, 64x64 tiles via LDS.
// grid: (12*8, 64)
__global__ __launch_bounds__(256) void convert_xT(const float* __restrict__ x,
                                                  unsigned short* __restrict__ xT) {
    __shared__ float tile[64][65];  // [cn_local][t_local], +1 pad breaks conflicts
    int b = blockIdx.y;
    int cnTile = blockIdx.x % 12;
    int tTile = blockIdx.x / 12;
    int tid = threadIdx.x;
    int cg = tid & 15;   // col group (16 x float4 = 64)
    int rr = tid >> 4;   // 16 rows per pass
    const float* xb = x + (size_t)b * KD * TDIM + (size_t)(cnTile * 64) * TDIM + tTile * 64;
#pragma unroll
    for (int p = 0; p < 4; ++p) {
        int r = p * 16 + rr;
        float4 v = *(const float4*)(xb + (size_t)r * TDIM + cg * 4);
        tile[r][cg * 4 + 0] = v.x;
        tile[r][cg * 4 + 1] = v.y;
        tile[r][cg * 4 + 2] = v.z;
        tile[r][cg * 4 + 3] = v.w;
    }
    __syncthreads();
    unsigned short* dst = xT + (size_t)b * TDIM * KD + (size_t)(tTile * 64) * KD + cnTile * 64;
#pragma unroll
    for (int p = 0; p < 4; ++p) {
        int t = p * 16 + rr;
        ushort4 pk;
        pk.x = f2bf(tile[cg * 4 + 0][t]);
        pk.y = f2bf(tile[cg * 4 + 1][t]);
        pk.z = f2bf(tile[cg * 4 + 2][t]);
        pk.w = f2bf(tile[cg * 4 + 3][t]);
        *(ushort4*)(dst + (size_t)t * KD + cg * 4) = pk;
    }
}

// ---------------------------------------------------------------------------
// gemm_cheb: out_b = W @ x_b (both operands staged [spatial][k] in LDS).
// grid: (6*4, 64); 256 thr = 4 waves (2x2 of 64x64), 16x16x32 bf16 MFMA.
__global__ __launch_bounds__(256) void gemm_cheb(const unsigned short* __restrict__ W,
                                                 const unsigned short* __restrict__ xT,
                                                 float* __restrict__ out) {
    __shared__ __attribute__((aligned(16))) unsigned short As[BM * BK];  // [row][k]
    __shared__ __attribute__((aligned(16))) unsigned short Bs[BN * BK];  // [t][k]
    int b = blockIdx.y;
    int mtile = blockIdx.x % 6;
    int ntile = blockIdx.x / 6;
    int tid = threadIdx.x;
    int wave = tid >> 6;
    int lane = tid & 63;
    int quad = lane >> 4;
    int l16 = lane & 15;
    int wm = wave >> 1, wn = wave & 1;

    const unsigned short* gA = W + (size_t)(mtile * BM) * KD;
    const unsigned short* gB = xT + (size_t)b * TDIM * KD + (size_t)(ntile * BN) * KD;

    int lrow = lane >> 2;    // 0..15 rows within a 16-row segment
    int lchunk = lane & 3;   // 0..3 chunks of 8 bf16
    int s0 = wave * 2;

    const float4v zero4 = {0.f, 0.f, 0.f, 0.f};
    float4v acc[4][4];
#pragma unroll
    for (int i = 0; i < 4; ++i)
#pragma unroll
        for (int j = 0; j < 4; ++j) acc[i][j] = zero4;

    for (int kt = 0; kt < KD / BK; ++kt) {
        __syncthreads();
        int k0 = kt * BK;
#pragma unroll
        for (int j = 0; j < 2; ++j) {
            int s = s0 + j;                  // segment 0..7 -> rows s*16..s*16+15
            int row = s * 16 + lrow;
            const unsigned short* srcA = gA + (size_t)row * KD + k0 + lchunk * 8;
            const unsigned short* srcB = gB + (size_t)row * KD + k0 + lchunk * 8;
            __builtin_amdgcn_global_load_lds(
                (const __attribute__((address_space(1))) void*)srcA,
                (__attribute__((address_space(3))) void*)(As + s * 512), 16, 0, 0);
            __builtin_amdgcn_global_load_lds(
                (const __attribute__((address_space(1))) void*)srcB,
                (__attribute__((address_space(3))) void*)(Bs + s * 512), 16, 0, 0);
        }
        __syncthreads();
        short8v a[4], bb[4];
#pragma unroll
        for (int i = 0; i < 4; ++i)
            a[i] = *(const short8v*)(As + (wm * 64 + i * 16 + l16) * BK + quad * 8);
#pragma unroll
        for (int j = 0; j < 4; ++j)
            bb[j] = *(const short8v*)(Bs + (wn * 64 + j * 16 + l16) * BK + quad * 8);
#pragma unroll
        for (int i = 0; i < 4; ++i)
#pragma unroll
            for (int j = 0; j < 4; ++j)
                acc[i][j] = __builtin_amdgcn_mfma_f32_16x16x32_bf16(a[i], bb[j], acc[i][j], 0, 0, 0);
    }

    // C/D layout (m89-verified): col = lane&15, row = quad*4 + reg
    float* outB = out + (size_t)b * MDIM * TDIM;
    int rbase = mtile * BM + wm * 64;
    int cbase = ntile * BN + wn * 64;
#pragma unroll
    for (int i = 0; i < 4; ++i) {
#pragma unroll
        for (int j = 0; j < 4; ++j) {
            int row0 = rbase + i * 16 + quad * 4;
            int col = cbase + j * 16 + l16;
#pragma unroll
            for (int r = 0; r < 4; ++r)
                outB[(size_t)(row0 + r) * TDIM + col] = acc[i][j][r];
        }
    }
}

// ---------------------------------------------------------------------------
extern "C" void kernel_launch(void* const* d_in, const int* in_sizes, int n_in,
                              void* d_out, int out_size, void* d_ws, size_t ws_size,
                              hipStream_t stream) {
    const float* x = (const float*)d_in[0];      // (64,32,24,512) fp32
    const float* adj = (const float*)d_in[1];    // (24,24) fp32
    const float* Theta = (const float*)d_in[2];  // (3,32,32) fp32
    float* out = (float*)d_out;                  // (64,32,24,512) fp32

    // ws layout: xT bf16 [64][512][768] (48 MB), then W bf16 [768][768] (1.125 MB)
    unsigned short* xT = (unsigned short*)d_ws;
    unsigned short* W = (unsigned short*)((char*)d_ws + (size_t)BATCH * TDIM * KD * 2);

    prep_w<<<64, 256, 0, stream>>>(adj, Theta, W);
    convert_xT<<<dim3(12 * 8, BATCH), 256, 0, stream>>>(x, xT);
    gemm_cheb<<<dim3(6 * 4, BATCH), 256, 0, stream>>>(W, xT, out);
}

// Round 3
// 245.271 us; speedup vs baseline: 1.0299x; 1.0299x over previous
//
#include <hip/hip_runtime.h>
#include <stdint.h>

// Cheb graph conv: out[b,o,m,t] = sum_{k,n,c} T_k[n,m] x[b,c,n,t] Theta[k,c,o]
// Folded:  W[(o,m)][(c,n)] = sum_k T_k[n,m] Theta[k,c,o]
//          out_b (768x512) = W @ x_b (768x512) per batch, bf16 MFMA.
// R3: pack both operands as contiguous 8 KB per-(tile,k-step) blobs so GEMM
// staging is fully coalesced (R2 staged 64 B rows @ stride 1536 B -> 3.2 TB/s cap).

#define NV 24
#define CIN 32
#define COUT 32
#define TDIM 512
#define BATCH 64
#define MDIM 768   // COUT*NV
#define KD 768     // CIN*NV
#define BM 128
#define BN 128
#define BK 32
#define NKT (KD / BK)    // 24
#define NTT (TDIM / BN)  // 4
#define NMT (MDIM / BM)  // 6
#define BLOB (BM * BK)   // 4096 shorts = 8 KB

typedef __attribute__((ext_vector_type(8))) short short8v;  // 8 bf16
typedef __attribute__((ext_vector_type(4))) float float4v;  // 4 fp32 acc

__device__ inline unsigned short f2bf(float f) {
    unsigned int u = __float_as_uint(f);
    unsigned int r = (u + 0x7fffu + ((u >> 16) & 1u)) >> 16;
    return (unsigned short)r;
}

// ---------------------------------------------------------------------------
// prep_w: 64 blocks x 256 thr; writes Wp packed [mt][kt][128 m][32 k] bf16.
// NV*NV=576 > 256 threads: per-element phases must be strided loops.
__global__ __launch_bounds__(256) void prep_w(const float* __restrict__ adj,
                                              const float* __restrict__ Theta,
                                              unsigned short* __restrict__ Wp) {
    __shared__ float adjS[NV * NV];
    __shared__ float disS[NV];
    __shared__ float LS[NV * NV];
    __shared__ float T2S[NV * NV];
    int tid = threadIdx.x;
    for (int e = tid; e < NV * NV; e += 256) adjS[e] = adj[e];
    __syncthreads();
    if (tid < NV) {
        float d = 0.f;
        for (int j = 0; j < NV; ++j) d += adjS[tid * NV + j];
        disS[tid] = (d > 0.f) ? rsqrtf(d) : 0.f;
    }
    __syncthreads();
    for (int e = tid; e < NV * NV; e += 256) {
        int i = e / NV, j = e % NV;
        LS[e] = disS[i] * adjS[j * NV + i] * disS[j];  // L = D^-1/2 A^T D^-1/2
    }
    __syncthreads();
    for (int e = tid; e < NV * NV; e += 256) {
        int i = e / NV, j = e % NV;
        float s = 0.f;
        for (int p = 0; p < NV; ++p) s += LS[i * NV + p] * LS[p * NV + j];
        T2S[e] = 2.f * s - (i == j ? 1.f : 0.f);
    }
    __syncthreads();
    int r0 = blockIdx.x * (MDIM / 64);  // 12 rows per block
    for (int e = tid; e < (MDIM / 64) * KD; e += 256) {
        int lr = e / KD, col = e % KD;
        int row = r0 + lr;
        int o = row / NV, m = row % NV;
        int c = col / NV, n = col % NV;
        float th0 = Theta[0 * CIN * COUT + c * COUT + o];
        float th1 = Theta[1 * CIN * COUT + c * COUT + o];
        float th2 = Theta[2 * CIN * COUT + c * COUT + o];
        float v = (n == m ? th0 : 0.f) + LS[n * NV + m] * th1 + T2S[n * NV + m] * th2;
        size_t idx = (((size_t)(row >> 7) * NKT + (col >> 5)) * BM + (row & 127)) * BK + (col & 31);
        Wp[idx] = f2bf(v);
    }
}

// ---------------------------------------------------------------------------
// convert_xP: x[b][cn][t] fp32 -> xP packed [b][tt][kt][128 t][32 k] bf16.
// grid (NKT*NTT, BATCH) = (96, 64), 256 thr.
__global__ __launch_bounds__(256) void convert_xP(const float* __restrict__ x,
                                                  unsigned short* __restrict__ xP) {
    __shared__ float tile[BK][133];  // [k][t]; 133 % 32 == 5 -> phase-2 reads conflict-free
    int kt = blockIdx.x % NKT;
    int tt = blockIdx.x / NKT;
    int b = blockIdx.y;
    int tid = threadIdx.x;
    const float* src = x + (size_t)b * KD * TDIM + (size_t)(kt * BK) * TDIM + tt * BN;
    // phase 1: float4-coalesced global reads (two 512 B rows per wave-instr)
#pragma unroll
    for (int p = 0; p < 4; ++p) {
        int e = p * 256 + tid;
        int r = e >> 5, c4 = e & 31;
        float4 v = *(const float4*)(src + (size_t)r * TDIM + c4 * 4);
        tile[r][c4 * 4 + 0] = v.x;
        tile[r][c4 * 4 + 1] = v.y;
        tile[r][c4 * 4 + 2] = v.z;
        tile[r][c4 * 4 + 3] = v.w;
    }
    __syncthreads();
    // phase 2: pack [t][32k]; per wave-instr lanes cover 1 KB contiguous
    unsigned short* dst = xP + ((size_t)(b * NTT + tt) * NKT + kt) * BLOB;
    int kq = tid & 7, tb = tid >> 3;
#pragma unroll
    for (int p = 0; p < 4; ++p) {
        int t = p * 32 + tb;
        ushort4 pk;
        pk.x = f2bf(tile[kq * 4 + 0][t]);
        pk.y = f2bf(tile[kq * 4 + 1][t]);
        pk.z = f2bf(tile[kq * 4 + 2][t]);
        pk.w = f2bf(tile[kq * 4 + 3][t]);
        *(ushort4*)(dst + t * BK + kq * 4) = pk;
    }
}

// ---------------------------------------------------------------------------
// gemm_cheb: out_b tile = W tile @ x tile; blob-streamed staging.
// grid (NMT*NTT, BATCH) = (24, 64); 256 thr = 4 waves (2x2 of 64x64).
__global__ __launch_bounds__(256) void gemm_cheb(const unsigned short* __restrict__ Wp,
                                                 const unsigned short* __restrict__ xP,
                                                 float* __restrict__ out) {
    __shared__ __attribute__((aligned(16))) unsigned short As[BLOB];  // [m][k]
    __shared__ __attribute__((aligned(16))) unsigned short Bs[BLOB];  // [t][k]
    int b = blockIdx.y;
    int mt = blockIdx.x % NMT;
    int tt = blockIdx.x / NMT;
    int tid = threadIdx.x;
    int wave = tid >> 6;
    int lane = tid & 63;
    int quad = lane >> 4;
    int l16 = lane & 15;
    int wm = wave >> 1, wn = wave & 1;

    const unsigned short* Ab = Wp + (size_t)mt * NKT * BLOB;
    const unsigned short* Bb = xP + (size_t)(b * NTT + tt) * NKT * BLOB;

    const float4v zero4 = {0.f, 0.f, 0.f, 0.f};
    float4v acc[4][4];
#pragma unroll
    for (int i = 0; i < 4; ++i)
#pragma unroll
        for (int j = 0; j < 4; ++j) acc[i][j] = zero4;

    for (int kt = 0; kt < NKT; ++kt) {
        __syncthreads();
        const unsigned short* abase = Ab + (size_t)kt * BLOB;
        const unsigned short* bbase = Bb + (size_t)kt * BLOB;
#pragma unroll
        for (int h = 0; h < 2; ++h) {
            // lane's src = base + h*2048 + tid*8 shorts (16 B/lane, contiguous);
            // lds dst = wave-uniform base, HW appends lane*16 B.
            const unsigned short* sa = abase + (h * 256 + tid) * 8;
            const unsigned short* sb = bbase + (h * 256 + tid) * 8;
            unsigned short* da = As + (h * 256 + wave * 64) * 8;
            unsigned short* db = Bs + (h * 256 + wave * 64) * 8;
            __builtin_amdgcn_global_load_lds(
                (const __attribute__((address_space(1))) void*)sa,
                (__attribute__((address_space(3))) void*)da, 16, 0, 0);
            __builtin_amdgcn_global_load_lds(
                (const __attribute__((address_space(1))) void*)sb,
                (__attribute__((address_space(3))) void*)db, 16, 0, 0);
        }
        __syncthreads();
        short8v a[4], bb[4];
#pragma unroll
        for (int i = 0; i < 4; ++i)
            a[i] = *(const short8v*)(As + (wm * 64 + i * 16 + l16) * BK + quad * 8);
#pragma unroll
        for (int j = 0; j < 4; ++j)
            bb[j] = *(const short8v*)(Bs + (wn * 64 + j * 16 + l16) * BK + quad * 8);
#pragma unroll
        for (int i = 0; i < 4; ++i)
#pragma unroll
            for (int j = 0; j < 4; ++j)
                acc[i][j] = __builtin_amdgcn_mfma_f32_16x16x32_bf16(a[i], bb[j], acc[i][j], 0, 0, 0);
    }

    // C/D layout (m89): col = lane&15, row = quad*4 + reg
    float* outB = out + (size_t)b * MDIM * TDIM;
    int rbase = mt * BM + wm * 64;
    int cbase = tt * BN + wn * 64;
#pragma unroll
    for (int i = 0; i < 4; ++i) {
#pragma unroll
        for (int j = 0; j < 4; ++j) {
            int row0 = rbase + i * 16 + quad * 4;
            int col = cbase + j * 16 + l16;
#pragma unroll
            for (int r = 0; r < 4; ++r)
                outB[(size_t)(row0 + r) * TDIM + col] = acc[i][j][r];
        }
    }
}

// ---------------------------------------------------------------------------
extern "C" void kernel_launch(void* const* d_in, const int* in_sizes, int n_in,
                              void* d_out, int out_size, void* d_ws, size_t ws_size,
                              hipStream_t stream) {
    const float* x = (const float*)d_in[0];      // (64,32,24,512) fp32
    const float* adj = (const float*)d_in[1];    // (24,24) fp32
    const float* Theta = (const float*)d_in[2];  // (3,32,32) fp32
    float* out = (float*)d_out;                  // (64,32,24,512) fp32

    // ws: xP bf16 packed 48 MB, then Wp bf16 packed 1.125 MB
    unsigned short* xP = (unsigned short*)d_ws;
    unsigned short* Wp = (unsigned short*)((char*)d_ws + (size_t)BATCH * TDIM * KD * 2);

    prep_w<<<64, 256, 0, stream>>>(adj, Theta, Wp);
    convert_xP<<<dim3(NKT * NTT, BATCH), 256, 0, stream>>>(x, xP);
    gemm_cheb<<<dim3(NMT * NTT, BATCH), 256, 0, stream>>>(Wp, xP, out);
}

// Round 4
// 236.696 us; speedup vs baseline: 1.0672x; 1.0362x over previous
//
#include <hip/hip_runtime.h>
#include <hip/hip_bf16.h>
#include <stdint.h>

// Cheb graph conv: out[b,o,m,t] = sum_{k,n,c} T_k[n,m] x[b,c,n,t] Theta[k,c,o]
// Folded:  W[(o,m)][(c,n)] = sum_k T_k[n,m] Theta[k,c,o]
//          out_b (768x512) = W @ x_b (768x512) per batch, bf16 MFMA.
// R4: FUSED — gemm reads x fp32 directly, stages [32k][128t] tile via
// global_load_lds with XOR-swizzled t4 blocks (conflict-free transposed
// fragment reads), converts to bf16 in-register. No xP intermediate, no
// convert kernel, ws shrinks 49 MB -> 1.125 MB. XCD swizzle co-locates the
// 6 mt-sharers of each x-slice on one XCD for L2 reuse.

#define NV 24
#define CIN 32
#define COUT 32
#define TDIM 512
#define BATCH 64
#define MDIM 768   // COUT*NV
#define KD 768     // CIN*NV
#define BM 128
#define BN 128
#define BK 32
#define NKT (KD / BK)    // 24
#define NTT (TDIM / BN)  // 4
#define NMT (MDIM / BM)  // 6
#define BLOB (BM * BK)   // 4096 shorts = 8 KB

typedef __attribute__((ext_vector_type(8))) short short8v;  // 8 bf16
typedef __attribute__((ext_vector_type(4))) float float4v;  // 4 fp32 acc

__device__ inline unsigned short f2bf(float f) {
    unsigned int u = __float_as_uint(f);
    unsigned int r = (u + 0x7fffu + ((u >> 16) & 1u)) >> 16;
    return (unsigned short)r;
}

// ---------------------------------------------------------------------------
// prep_w: 64 blocks x 256 thr; writes Wp packed [mt][kt][128 m][32 k] bf16.
// NV*NV=576 > 256 threads: per-element phases must be strided loops.
__global__ __launch_bounds__(256) void prep_w(const float* __restrict__ adj,
                                              const float* __restrict__ Theta,
                                              unsigned short* __restrict__ Wp) {
    __shared__ float adjS[NV * NV];
    __shared__ float disS[NV];
    __shared__ float LS[NV * NV];
    __shared__ float T2S[NV * NV];
    int tid = threadIdx.x;
    for (int e = tid; e < NV * NV; e += 256) adjS[e] = adj[e];
    __syncthreads();
    if (tid < NV) {
        float d = 0.f;
        for (int j = 0; j < NV; ++j) d += adjS[tid * NV + j];
        disS[tid] = (d > 0.f) ? rsqrtf(d) : 0.f;
    }
    __syncthreads();
    for (int e = tid; e < NV * NV; e += 256) {
        int i = e / NV, j = e % NV;
        LS[e] = disS[i] * adjS[j * NV + i] * disS[j];  // L = D^-1/2 A^T D^-1/2
    }
    __syncthreads();
    for (int e = tid; e < NV * NV; e += 256) {
        int i = e / NV, j = e % NV;
        float s = 0.f;
        for (int p = 0; p < NV; ++p) s += LS[i * NV + p] * LS[p * NV + j];
        T2S[e] = 2.f * s - (i == j ? 1.f : 0.f);
    }
    __syncthreads();
    int r0 = blockIdx.x * (MDIM / 64);  // 12 rows per block
    for (int e = tid; e < (MDIM / 64) * KD; e += 256) {
        int lr = e / KD, col = e % KD;
        int row = r0 + lr;
        int o = row / NV, m = row % NV;
        int c = col / NV, n = col % NV;
        float th0 = Theta[0 * CIN * COUT + c * COUT + o];
        float th1 = Theta[1 * CIN * COUT + c * COUT + o];
        float th2 = Theta[2 * CIN * COUT + c * COUT + o];
        float v = (n == m ? th0 : 0.f) + LS[n * NV + m] * th1 + T2S[n * NV + m] * th2;
        size_t idx = (((size_t)(row >> 7) * NKT + (col >> 5)) * BM + (row & 127)) * BK + (col & 31);
        Wp[idx] = f2bf(v);
    }
}

// ---------------------------------------------------------------------------
// gemm_fused: out tile (128m x 128t) = Wp tile @ x^T tile, transposing x
// fp32->bf16 on the fly through an XOR-swizzled LDS tile.
// grid 1536 blocks (1-D, XCD-swizzled); 256 thr = 4 waves (2x2 of 64x64).
__global__ __launch_bounds__(256) void gemm_fused(const unsigned short* __restrict__ Wp,
                                                  const float* __restrict__ x,
                                                  float* __restrict__ out) {
    __shared__ __attribute__((aligned(16))) unsigned short As[BLOB];   // [m][k] bf16
    __shared__ __attribute__((aligned(16))) float xF[BK * BN];         // [k][t4 swizzled] fp32

    // XCD swizzle: id = (g>>3)*48 + mt*8 + (g&7); sharers (same g, 6 mt) are
    // 8 apart -> same XCD under round-robin, nearly concurrent.
    int id = blockIdx.x;
    int hi = id / 48;
    int rem = id - hi * 48;
    int mt = rem >> 3;               // 0..5
    int g = hi * 8 + (rem & 7);      // 0..255
    int b = g >> 2;
    int tt = g & 3;

    int tid = threadIdx.x;
    int wave = tid >> 6;
    int lane = tid & 63;
    int quad = lane >> 4;
    int l16 = lane & 15;
    int wm = wave >> 1, wn = wave & 1;

    const unsigned short* Ab = Wp + (size_t)mt * NKT * BLOB;
    const float* xb = x + (size_t)b * KD * TDIM + tt * BN;  // rows [k][512], col slice

    const float4v zero4 = {0.f, 0.f, 0.f, 0.f};
    float4v acc[4][4];
#pragma unroll
    for (int i = 0; i < 4; ++i)
#pragma unroll
        for (int j = 0; j < 4; ++j) acc[i][j] = zero4;

    // Per-lane staging indices (loop-invariant parts)
    // A: 2 rounds of 256 lanes x 16 B
    // xF: 4 rounds; lin = h*256+tid; k = lin>>5 (0..31), t4 = lin&31;
    //     src t4 block = t4 ^ ((k>>3)*2)  [16 B granule swizzle]
    for (int kt = 0; kt < NKT; ++kt) {
        __syncthreads();
        const unsigned short* abase = Ab + (size_t)kt * BLOB;
        const float* xrow = xb + (size_t)(kt * BK) * TDIM;
#pragma unroll
        for (int h = 0; h < 2; ++h) {
            const unsigned short* sa = abase + (h * 256 + tid) * 8;
            unsigned short* da = As + (h * 256 + wave * 64) * 8;
            __builtin_amdgcn_global_load_lds(
                (const __attribute__((address_space(1))) void*)sa,
                (__attribute__((address_space(3))) void*)da, 16, 0, 0);
        }
#pragma unroll
        for (int h = 0; h < 4; ++h) {
            int lin = h * 256 + tid;
            int k = lin >> 5;
            int t4 = lin & 31;
            int t4src = t4 ^ ((k >> 3) * 2);
            const float* sx = xrow + (size_t)k * TDIM + t4src * 4;
            float* dx = xF + (h * 1024 + wave * 256);
            __builtin_amdgcn_global_load_lds(
                (const __attribute__((address_space(1))) void*)sx,
                (__attribute__((address_space(3))) void*)dx, 16, 0, 0);
        }
        __syncthreads();

        // A fragments: [m][k] contiguous, ds_read_b128
        short8v a[4];
#pragma unroll
        for (int i = 0; i < 4; ++i)
            a[i] = *(const short8v*)(As + (wm * 64 + i * 16 + l16) * BK + quad * 8);

        // B fragments: transposed read from swizzled fp32 tile + cvt to bf16.
        // lane needs x[k = quad*8+jj][tloc], tloc = wn*64 + j*16 + l16.
        short8v bb[4];
#pragma unroll
        for (int j = 0; j < 4; ++j) {
            int tloc = wn * 64 + j * 16 + l16;
            int t4 = tloc >> 2, ti = tloc & 3;
            const float* bp = xF + quad * 8 * BN + ((t4 ^ (quad * 2)) << 2) + ti;
            float v0 = bp[0 * BN], v1 = bp[1 * BN], v2 = bp[2 * BN], v3 = bp[3 * BN];
            float v4 = bp[4 * BN], v5 = bp[5 * BN], v6 = bp[6 * BN], v7 = bp[7 * BN];
            union { short8v s; __hip_bfloat162 h[4]; } u;
            u.h[0] = __float22bfloat162_rn({v0, v1});
            u.h[1] = __float22bfloat162_rn({v2, v3});
            u.h[2] = __float22bfloat162_rn({v4, v5});
            u.h[3] = __float22bfloat162_rn({v6, v7});
            bb[j] = u.s;
        }
#pragma unroll
        for (int i = 0; i < 4; ++i)
#pragma unroll
            for (int j = 0; j < 4; ++j)
                acc[i][j] = __builtin_amdgcn_mfma_f32_16x16x32_bf16(a[i], bb[j], acc[i][j], 0, 0, 0);
    }

    // C/D layout (m89): col = lane&15, row = quad*4 + reg
    float* outB = out + (size_t)b * MDIM * TDIM;
    int rbase = mt * BM + wm * 64;
    int cbase = tt * BN + wn * 64;
#pragma unroll
    for (int i = 0; i < 4; ++i) {
#pragma unroll
        for (int j = 0; j < 4; ++j) {
            int row0 = rbase + i * 16 + quad * 4;
            int col = cbase + j * 16 + l16;
#pragma unroll
            for (int r = 0; r < 4; ++r)
                outB[(size_t)(row0 + r) * TDIM + col] = acc[i][j][r];
        }
    }
}

// ---------------------------------------------------------------------------
extern "C" void kernel_launch(void* const* d_in, const int* in_sizes, int n_in,
                              void* d_out, int out_size, void* d_ws, size_t ws_size,
                              hipStream_t stream) {
    const float* x = (const float*)d_in[0];      // (64,32,24,512) fp32
    const float* adj = (const float*)d_in[1];    // (24,24) fp32
    const float* Theta = (const float*)d_in[2];  // (3,32,32) fp32
    float* out = (float*)d_out;                  // (64,32,24,512) fp32

    // ws: Wp bf16 packed blobs only (1.125 MB)
    unsigned short* Wp = (unsigned short*)d_ws;

    prep_w<<<64, 256, 0, stream>>>(adj, Theta, Wp);
    gemm_fused<<<NMT * NTT * BATCH, 256, 0, stream>>>(Wp, x, out);
}

// Round 5
// 221.238 us; speedup vs baseline: 1.1418x; 1.0699x over previous
//
#include <hip/hip_runtime.h>
#include <hip/hip_bf16.h>
#include <stdint.h>

// Cheb graph conv: out[b,o,m,t] = sum_{k,n,c} T_k[n,m] x[b,c,n,t] Theta[k,c,o]
// Folded:  W[(o,m)][(c,n)] = sum_k T_k[n,m] Theta[k,c,o]
//          out_b (768x512) = W @ x_b (768x512) per batch, bf16 MFMA.
// R5: fused + VGPR-pipelined. x transposed fp32->bf16 via registers + two
// ds_write_b128 per thread into Bs[t][k] (80 B row stride = 8-way bank
// spread); A staged via dwordx4->ds_write_b128. NO global_load_lds, so
// barriers carry no vmcnt(0) drain and next-kt global loads overlap MFMA.

#define NV 24
#define CIN 32
#define COUT 32
#define TDIM 512
#define BATCH 64
#define MDIM 768   // COUT*NV
#define KD 768     // CIN*NV
#define BM 128
#define BN 128
#define BK 32
#define NKT (KD / BK)    // 24
#define NTT (TDIM / BN)  // 4
#define NMT (MDIM / BM)  // 6
#define BLOB (BM * BK)   // 4096 shorts = 8 KB
#define BSTRIDE 40       // Bs row stride in shorts (80 B): 20t mod 32 -> 8-way spread

typedef __attribute__((ext_vector_type(8))) short short8v;  // 8 bf16
typedef __attribute__((ext_vector_type(4))) float float4v;  // 4 fp32 acc

__device__ inline unsigned short f2bf(float f) {
    unsigned int u = __float_as_uint(f);
    unsigned int r = (u + 0x7fffu + ((u >> 16) & 1u)) >> 16;
    return (unsigned short)r;
}

// ---------------------------------------------------------------------------
// prep_w: 64 blocks x 256 thr; writes Wp packed [mt][kt][128 m][32 k] bf16.
// NV*NV=576 > 256 threads: per-element phases must be strided loops.
__global__ __launch_bounds__(256) void prep_w(const float* __restrict__ adj,
                                              const float* __restrict__ Theta,
                                              unsigned short* __restrict__ Wp) {
    __shared__ float adjS[NV * NV];
    __shared__ float disS[NV];
    __shared__ float LS[NV * NV];
    __shared__ float T2S[NV * NV];
    int tid = threadIdx.x;
    for (int e = tid; e < NV * NV; e += 256) adjS[e] = adj[e];
    __syncthreads();
    if (tid < NV) {
        float d = 0.f;
        for (int j = 0; j < NV; ++j) d += adjS[tid * NV + j];
        disS[tid] = (d > 0.f) ? rsqrtf(d) : 0.f;
    }
    __syncthreads();
    for (int e = tid; e < NV * NV; e += 256) {
        int i = e / NV, j = e % NV;
        LS[e] = disS[i] * adjS[j * NV + i] * disS[j];  // L = D^-1/2 A^T D^-1/2
    }
    __syncthreads();
    for (int e = tid; e < NV * NV; e += 256) {
        int i = e / NV, j = e % NV;
        float s = 0.f;
        for (int p = 0; p < NV; ++p) s += LS[i * NV + p] * LS[p * NV + j];
        T2S[e] = 2.f * s - (i == j ? 1.f : 0.f);
    }
    __syncthreads();
    int r0 = blockIdx.x * (MDIM / 64);  // 12 rows per block
    for (int e = tid; e < (MDIM / 64) * KD; e += 256) {
        int lr = e / KD, col = e % KD;
        int row = r0 + lr;
        int o = row / NV, m = row % NV;
        int c = col / NV, n = col % NV;
        float th0 = Theta[0 * CIN * COUT + c * COUT + o];
        float th1 = Theta[1 * CIN * COUT + c * COUT + o];
        float th2 = Theta[2 * CIN * COUT + c * COUT + o];
        float v = (n == m ? th0 : 0.f) + LS[n * NV + m] * th1 + T2S[n * NV + m] * th2;
        size_t idx = (((size_t)(row >> 7) * NKT + (col >> 5)) * BM + (row & 127)) * BK + (col & 31);
        Wp[idx] = f2bf(v);
    }
}

// ---------------------------------------------------------------------------
// gemm_fused: out tile (128m x 128t) = Wp tile @ x^T tile.
// grid 1536 (XCD-swizzled); 256 thr = 4 waves (2x2 of 64x64).
__global__ __launch_bounds__(256, 4) void gemm_fused(const unsigned short* __restrict__ Wp,
                                                     const float* __restrict__ x,
                                                     float* __restrict__ out) {
    __shared__ __attribute__((aligned(16))) unsigned short As[BM * BK];       // 8 KB  [m][k]
    __shared__ __attribute__((aligned(16))) unsigned short Bs[BN * BSTRIDE];  // 10 KB [t][k], 80 B rows

    // XCD swizzle: the 6 mt-sharers of an x-slice land on one XCD window.
    int id = blockIdx.x;
    int hi = id / 48;
    int rem = id - hi * 48;
    int mt = rem >> 3;               // 0..5
    int g = hi * 8 + (rem & 7);      // 0..255
    int b = g >> 2;
    int tt = g & 3;

    int tid = threadIdx.x;
    int wave = tid >> 6;
    int lane = tid & 63;
    int quad = lane >> 4;
    int l16 = lane & 15;
    int wm = wave >> 1, wn = wave & 1;
    int kq = wave;      // x-stage: this wave covers k = kq*8 .. kq*8+7
    int tp = lane;      // x-stage: this thread covers t = tp and tp+64

    const unsigned short* Ab = Wp + (size_t)mt * NKT * BLOB;
    const float* xb = x + (size_t)b * KD * TDIM + tt * BN;

    const float4v zero4 = {0.f, 0.f, 0.f, 0.f};
    float4v acc[4][4];
#pragma unroll
    for (int i = 0; i < 4; ++i)
#pragma unroll
        for (int j = 0; j < 4; ++j) acc[i][j] = zero4;

    // ---- prefetch registers ----
    uint4 Ar0, Ar1;
    float Xr[16];

    // prologue: load kt = 0
    {
        const uint4* ap = (const uint4*)Ab;
        Ar0 = ap[tid];
        Ar1 = ap[tid + 256];
        const float* xr = xb + (size_t)(kq * 8) * TDIM;
#pragma unroll
        for (int kk = 0; kk < 8; ++kk) {
            Xr[kk] = xr[(size_t)kk * TDIM + tp];
            Xr[8 + kk] = xr[(size_t)kk * TDIM + tp + 64];
        }
    }

    for (int kt = 0; kt < NKT; ++kt) {
        // pack current x regs -> bf16 (uses Xr/Ar; vmcnt wait lands here,
        // one full iteration after issue)
        union { short8v s; __hip_bfloat162 h[4]; } u0, u1;
#pragma unroll
        for (int i = 0; i < 4; ++i) {
            u0.h[i] = __float22bfloat162_rn({Xr[2 * i], Xr[2 * i + 1]});
            u1.h[i] = __float22bfloat162_rn({Xr[8 + 2 * i], Xr[8 + 2 * i + 1]});
        }
        uint4 a0 = Ar0, a1 = Ar1;

        __syncthreads();  // prior iter's fragment reads done (lgkm only)
        *(uint4*)(As + tid * 8) = a0;                 // byte tid*16
        *(uint4*)(As + 2048 + tid * 8) = a1;          // byte 4096 + tid*16
        *(short8v*)(Bs + tp * BSTRIDE + kq * 8) = u0.s;          // t = tp
        *(short8v*)(Bs + (tp + 64) * BSTRIDE + kq * 8) = u1.s;   // t = tp+64
        __syncthreads();

        // prefetch kt+1 (no barrier will drain these; MFMA covers latency)
        if (kt + 1 < NKT) {
            const uint4* ap = (const uint4*)(Ab + (size_t)(kt + 1) * BLOB);
            Ar0 = ap[tid];
            Ar1 = ap[tid + 256];
            const float* xr = xb + (size_t)((kt + 1) * BK + kq * 8) * TDIM;
#pragma unroll
            for (int kk = 0; kk < 8; ++kk) {
                Xr[kk] = xr[(size_t)kk * TDIM + tp];
                Xr[8 + kk] = xr[(size_t)kk * TDIM + tp + 64];
            }
        }

        short8v a[4], bb[4];
#pragma unroll
        for (int i = 0; i < 4; ++i)
            a[i] = *(const short8v*)(As + (wm * 64 + i * 16 + l16) * BK + quad * 8);
#pragma unroll
        for (int j = 0; j < 4; ++j)
            bb[j] = *(const short8v*)(Bs + (wn * 64 + j * 16 + l16) * BSTRIDE + quad * 8);
#pragma unroll
        for (int i = 0; i < 4; ++i)
#pragma unroll
            for (int j = 0; j < 4; ++j)
                acc[i][j] = __builtin_amdgcn_mfma_f32_16x16x32_bf16(a[i], bb[j], acc[i][j], 0, 0, 0);
    }

    // C/D layout (m89): col = lane&15, row = quad*4 + reg
    float* outB = out + (size_t)b * MDIM * TDIM;
    int rbase = mt * BM + wm * 64;
    int cbase = tt * BN + wn * 64;
#pragma unroll
    for (int i = 0; i < 4; ++i) {
#pragma unroll
        for (int j = 0; j < 4; ++j) {
            int row0 = rbase + i * 16 + quad * 4;
            int col = cbase + j * 16 + l16;
#pragma unroll
            for (int r = 0; r < 4; ++r)
                outB[(size_t)(row0 + r) * TDIM + col] = acc[i][j][r];
        }
    }
}

// ---------------------------------------------------------------------------
extern "C" void kernel_launch(void* const* d_in, const int* in_sizes, int n_in,
                              void* d_out, int out_size, void* d_ws, size_t ws_size,
                              hipStream_t stream) {
    const float* x = (const float*)d_in[0];      // (64,32,24,512) fp32
    const float* adj = (const float*)d_in[1];    // (24,24) fp32
    const float* Theta = (const float*)d_in[2];  // (3,32,32) fp32
    float* out = (float*)d_out;                  // (64,32,24,512) fp32

    // ws: Wp bf16 packed blobs only (1.125 MB)
    unsigned short* Wp = (unsigned short*)d_ws;

    prep_w<<<64, 256, 0, stream>>>(adj, Theta, Wp);
    gemm_fused<<<NMT * NTT * BATCH, 256, 0, stream>>>(Wp, x, out);
}